// Round 4
// baseline (491.241 us; speedup 1.0000x reference)
//
#include <hip/hip_runtime.h>
#include <math.h>

#define MTOT 65536   // B*T
#define DD   128
#define KK   1024
#define BETA 0.25f
#define TM   64      // rows per k_main block
#define NCH  64      // codes per chunk

typedef __attribute__((ext_vector_type(8))) short short8;
typedef __attribute__((ext_vector_type(4))) float float4v;

__device__ __forceinline__ unsigned bf16_rne(float x) {
    unsigned u = __float_as_uint(x);
    return (u + 0x7fffu + ((u >> 16) & 1u)) >> 16;
}

__device__ __forceinline__ void gload_lds16(const void* g, void* l) {
    __builtin_amdgcn_global_load_lds(
        (const __attribute__((address_space(1))) unsigned int*)g,
        (__attribute__((address_space(3))) unsigned int*)l, 16, 0, 0);
}

// --------- K0: codebook -> bf16 hi/lo PRE-SWIZZLED (for global_load_lds) ----
__global__ void k_norms(const float* __restrict__ e, ushort* __restrict__ bp,
                        float* __restrict__ nef, float* __restrict__ inef,
                        float* __restrict__ loss) {
    const int gw = blockIdx.x * 4 + (threadIdx.x >> 6);
    const int lane = threadIdx.x & 63;
    char* hb = (char*)bp;
    char* lb = hb + 262144;                   // lo part after hi part
    const int sub = lane & 3;
    for (int code = gw; code < KK; code += 256) {
        float2 ev = ((const float2*)(e + (size_t)code * DD))[lane];
        unsigned h0 = bf16_rne(ev.x), h1 = bf16_rne(ev.y);
        float l0f = ev.x - __uint_as_float(h0 << 16);
        float l1f = ev.y - __uint_as_float(h1 << 16);
        ushort2 hv; hv.x = (ushort)h0; hv.y = (ushort)h1;
        ushort2 lv; lv.x = (ushort)bf16_rne(l0f); lv.y = (ushort)bf16_rne(l1f);
        int sw = (((lane >> 2) * 16) ^ ((code & 7) << 4)) + sub * 4;
        *(ushort2*)(hb + code * 256 + sw) = hv;
        *(ushort2*)(lb + code * 256 + sw) = lv;
        float s = ev.x * ev.x + ev.y * ev.y;
        #pragma unroll
        for (int off = 32; off; off >>= 1) s += __shfl_down(s, off, 64);
        if (lane == 0) { nef[code] = s; inef[code] = 1.0f / sqrtf(s); }
    }
    if (blockIdx.x == 0 && threadIdx.x == 0) *loss = 0.0f;
}

// lexicographic (value, index) top-2 merge of (v1,i1,v2,i2) with (ov1..oi2)
__device__ __forceinline__ void merge2(float& v1, int& i1, float& v2, int& i2,
                                       float ov1, int oi1, float ov2, int oi2) {
    bool l1 = (ov1 < v1) || (ov1 == v1 && oi1 < i1);
    if (l1) {
        bool l2 = (ov2 < v1) || (ov2 == v1 && oi2 < i1);
        v2 = l2 ? ov2 : v1; i2 = l2 ? oi2 : i1;
        v1 = ov1; i1 = oi1;
    } else {
        bool l2 = (ov1 < v2) || (ov1 == v2 && oi1 < i2);
        if (l2) { v2 = ov1; i2 = oi1; }
    }
}

// --------- K1: swapped-operand MFMA (D row=code, col=z-row) ----------------
__launch_bounds__(256, 2)
__global__ void k_main(const float* __restrict__ z, float* __restrict__ sim,
                       const ushort* __restrict__ bpre,
                       const float* __restrict__ nef, const float* __restrict__ inef,
                       const float* __restrict__ e, float* __restrict__ zq,
                       float* __restrict__ idsf, float* __restrict__ loss) {
    // double-buffered B chunk: [buf][hi 16KB | lo 16KB] = 64 KB
    __shared__ __align__(16) ushort Bs[2 * 16384];
    __shared__ unsigned candL[TM];
    __shared__ float bs[4];

    const int t = threadIdx.x;
    const int w = t >> 6, lane = t & 63, cl = lane & 15, q = lane >> 4;
    const int mh = (w & 1) * 32, nh = (w >> 1) * 32;
    const int r0 = blockIdx.x * TM;

    auto STAGE = [&](int buf, int ch2) {
        const char* gb = (const char*)bpre + (size_t)ch2 * 16384;
        #pragma unroll
        for (int i = 0; i < 8; ++i) {
            int slot = i * 256 + t;                       // 0..2047, 16B each
            int goff = slot * 16 + ((slot >= 1024) ? 245760 : 0);  // lo part adj
            gload_lds16(gb + goff,
                        (char*)Bs + buf * 32768 + (i * 256 + (t & 0xFFC0)) * 16);
        }
    };

    // issue chunk-0 B staging first so it overlaps the A load/convert
    STAGE(0, 0);

    // ---- z: load directly, split to bf16 hi/lo in regs, |z|^2 per lane-row -
    short8 afh[2][4], afl[2][4];
    float pn0 = 0.0f, pn1 = 0.0f;
    const char* zb = (const char*)z;
    #pragma unroll
    for (int mt = 0; mt < 2; ++mt) {
        const char* rp = zb + (size_t)(r0 + mh + mt * 16 + cl) * 512;
        #pragma unroll
        for (int s = 0; s < 4; ++s) {
            float4v f0 = *(const float4v*)(rp + s * 128 + q * 32);
            float4v f1 = *(const float4v*)(rp + s * 128 + q * 32 + 16);
            short8 h, l;
            float ps = 0.0f;
            #pragma unroll
            for (int j = 0; j < 4; ++j) {
                float fx = f0[j];
                unsigned hu = bf16_rne(fx);
                h[j] = (short)hu;
                l[j] = (short)bf16_rne(fx - __uint_as_float(hu << 16));
                ps += fx * fx;
                float fy = f1[j];
                unsigned hw2 = bf16_rne(fy);
                h[j + 4] = (short)hw2;
                l[j + 4] = (short)bf16_rne(fy - __uint_as_float(hw2 << 16));
                ps += fy * fy;
            }
            afh[mt][s] = h; afl[mt][s] = l;
            if (mt == 0) pn0 += ps; else pn1 += ps;
        }
    }
    // all-q reduce: every lane ends with its row's |z|^2 (row = mh+zt*16+cl)
    pn0 += __shfl_xor(pn0, 16, 64); pn0 += __shfl_xor(pn0, 32, 64);
    pn1 += __shfl_xor(pn1, 16, 64); pn1 += __shfl_xor(pn1, 32, 64);
    float inzr[2]; inzr[0] = 1.0f / sqrtf(pn0); inzr[1] = 1.0f / sqrtf(pn1);
    __syncthreads();   // chunk-0 stage drained (vmcnt(0) at barrier)

    // per-lane top-2 per z-row (zt selects which of the lane's 2 rows)
    float b1v[2], b2v[2]; int b1i[2], b2i[2];
    #pragma unroll
    for (int s = 0; s < 2; ++s) { b1v[s] = 3.4e38f; b2v[s] = 3.4e38f; b1i[s] = 0; b2i[s] = 0; }

    const int swz = (cl & 7) << 4;
    for (int ch = 0; ch < 16; ++ch) {
        const int c0 = ch * NCH;
        const char* Bb = (const char*)Bs + (ch & 1) * 32768;
        if (ch < 15) STAGE((ch + 1) & 1, ch + 1);   // prefetch next chunk

        // codebook norms for this wave's 2x4 consecutive codes (float4 loads)
        float4v ne4[2], ine4[2];
        #pragma unroll
        for (int ct = 0; ct < 2; ++ct) {
            int cb = c0 + nh + ct * 16 + q * 4;
            ne4[ct]  = *(const float4v*)(nef + cb);
            ine4[ct] = *(const float4v*)(inef + cb);
        }

        float4v acc[2][2];   // [code-tile][z-tile]
        #pragma unroll
        for (int ct = 0; ct < 2; ++ct)
            #pragma unroll
            for (int zt = 0; zt < 2; ++zt) acc[ct][zt] = (float4v)(0.0f);

        // pass 0: Ch*Zh — load code-hi frags and HOLD for pass 2
        short8 bh0[4], bh1[4];
        #pragma unroll
        for (int s = 0; s < 4; ++s) {
            const int ko = (s * 64 + q * 16) ^ swz;
            bh0[s] = *(const short8*)(Bb + (nh + cl) * 256 + ko);
            bh1[s] = *(const short8*)(Bb + (nh + 16 + cl) * 256 + ko);
            acc[0][0] = __builtin_amdgcn_mfma_f32_16x16x32_bf16(bh0[s], afh[0][s], acc[0][0], 0, 0, 0);
            acc[0][1] = __builtin_amdgcn_mfma_f32_16x16x32_bf16(bh0[s], afh[1][s], acc[0][1], 0, 0, 0);
            acc[1][0] = __builtin_amdgcn_mfma_f32_16x16x32_bf16(bh1[s], afh[0][s], acc[1][0], 0, 0, 0);
            acc[1][1] = __builtin_amdgcn_mfma_f32_16x16x32_bf16(bh1[s], afh[1][s], acc[1][1], 0, 0, 0);
        }
        // pass 1: Cl*Zh
        #pragma unroll
        for (int s = 0; s < 4; ++s) {
            const int ko = (s * 64 + q * 16) ^ swz;
            short8 bl0 = *(const short8*)(Bb + 16384 + (nh + cl) * 256 + ko);
            short8 bl1 = *(const short8*)(Bb + 16384 + (nh + 16 + cl) * 256 + ko);
            acc[0][0] = __builtin_amdgcn_mfma_f32_16x16x32_bf16(bl0, afh[0][s], acc[0][0], 0, 0, 0);
            acc[0][1] = __builtin_amdgcn_mfma_f32_16x16x32_bf16(bl0, afh[1][s], acc[0][1], 0, 0, 0);
            acc[1][0] = __builtin_amdgcn_mfma_f32_16x16x32_bf16(bl1, afh[0][s], acc[1][0], 0, 0, 0);
            acc[1][1] = __builtin_amdgcn_mfma_f32_16x16x32_bf16(bl1, afh[1][s], acc[1][1], 0, 0, 0);
        }
        // pass 2: Ch*Zl (code-hi frags still in registers)
        #pragma unroll
        for (int s = 0; s < 4; ++s) {
            acc[0][0] = __builtin_amdgcn_mfma_f32_16x16x32_bf16(bh0[s], afl[0][s], acc[0][0], 0, 0, 0);
            acc[0][1] = __builtin_amdgcn_mfma_f32_16x16x32_bf16(bh0[s], afl[1][s], acc[0][1], 0, 0, 0);
            acc[1][0] = __builtin_amdgcn_mfma_f32_16x16x32_bf16(bh1[s], afl[0][s], acc[1][0], 0, 0, 0);
            acc[1][1] = __builtin_amdgcn_mfma_f32_16x16x32_bf16(bh1[s], afl[1][s], acc[1][1], 0, 0, 0);
        }

        __syncthreads();   // drains prefetch vmcnt; all waves done reading Bb

        // epilogue: per lane 4 consecutive codes of one z-row -> float4 stores
        // dist drops |z|^2 (constant per row: top-2 selection invariant)
        #pragma unroll
        for (int zt = 0; zt < 2; ++zt) {
            const float inz = inzr[zt];
            const size_t rowg = (size_t)(r0 + mh + zt * 16 + cl);
            #pragma unroll
            for (int ct = 0; ct < 2; ++ct) {
                const int cb = c0 + nh + ct * 16 + q * 4;
                float4v d = acc[ct][zt];
                float4v sv;
                #pragma unroll
                for (int j = 0; j < 4; ++j) sv[j] = d[j] * inz * ine4[ct][j];
                *(float4v*)(sim + rowg * KK + cb) = sv;
                #pragma unroll
                for (int j = 0; j < 4; ++j) {
                    float dist = fmaf(-2.0f, d[j], ne4[ct][j]);
                    int col = cb + j;
                    if (dist < b1v[zt]) {
                        b2v[zt] = b1v[zt]; b2i[zt] = b1i[zt];
                        b1v[zt] = dist;    b1i[zt] = col;
                    } else if (dist < b2v[zt]) {
                        b2v[zt] = dist; b2i[zt] = col;
                    }
                }
            }
        }
    }

    // cross-lane merge over the 4 q-lanes (same z-row) via shfl_xor
    #pragma unroll
    for (int zt = 0; zt < 2; ++zt) {
        #pragma unroll
        for (int off = 16; off <= 32; off <<= 1) {
            float ov1 = __shfl_xor(b1v[zt], off, 64);
            int   oi1 = __shfl_xor(b1i[zt], off, 64);
            float ov2 = __shfl_xor(b2v[zt], off, 64);
            int   oi2 = __shfl_xor(b2i[zt], off, 64);
            merge2(b1v[zt], b1i[zt], b2v[zt], b2i[zt], ov1, oi1, ov2, oi2);
        }
    }
    // cross-wave (two code halves) merge via tiny LDS table [64 rows][2][4]
    float* top = (float*)Bs;
    if (q == 0) {
        #pragma unroll
        for (int zt = 0; zt < 2; ++zt) {
            int row = mh + zt * 16 + cl;
            float4v v;
            v[0] = b1v[zt]; v[1] = __int_as_float(b1i[zt]);
            v[2] = b2v[zt]; v[3] = __int_as_float(b2i[zt]);
            *(float4v*)(top + (row * 2 + (w >> 1)) * 4) = v;
        }
    }
    __syncthreads();
    if (t < TM) {
        float4v e0 = *(const float4v*)(top + (t * 2 + 0) * 4);
        float4v e1 = *(const float4v*)(top + (t * 2 + 1) * 4);
        float v1 = e0[0], v2 = e0[2];
        int   i1 = __float_as_int(e0[1]), i2 = __float_as_int(e0[3]);
        merge2(v1, i1, v2, i2, e1[0], __float_as_int(e1[1]), e1[2], __float_as_int(e1[3]));
        candL[t] = (unsigned)i1 | ((unsigned)i2 << 16);
    }
    __syncthreads();

    // ---- fused exact fp32 re-rank of top-2 (identical math to old K2) ------
    float wsum = 0.0f;
    const int rloc = w * 16;
    for (int i = 0; i < 16; ++i) {
        int row = r0 + rloc + i;
        unsigned pk = candL[rloc + i];
        int c1 = (int)(pk & 0xffffu), c2 = (int)(pk >> 16);
        float2 zv = ((const float2*)(z + (size_t)row * DD))[lane];
        float2 e1 = ((const float2*)(e + (size_t)c1 * DD))[lane];
        float2 e2 = ((const float2*)(e + (size_t)c2 * DD))[lane];
        float v0 = zv.x * zv.x + zv.y * zv.y;   // |z|^2
        float v1 = zv.x * e1.x + zv.y * e1.y;   // z.e1
        float v2 = zv.x * e2.x + zv.y * e2.y;   // z.e2
        float v3 = e1.x * e1.x + e1.y * e1.y;   // |e1|^2
        float v4 = e2.x * e2.x + e2.y * e2.y;   // |e2|^2
        #pragma unroll
        for (int off = 32; off; off >>= 1) {
            v0 += __shfl_down(v0, off, 64);
            v1 += __shfl_down(v1, off, 64);
            v2 += __shfl_down(v2, off, 64);
            v3 += __shfl_down(v3, off, 64);
            v4 += __shfl_down(v4, off, 64);
        }
        int choice = 0; float ssq = 0.0f;
        if (lane == 0) {
            float d1 = fmaf(-2.0f, v1, v0 + v3);
            float d2 = fmaf(-2.0f, v2, v0 + v4);
            choice = (d2 < d1 || (d2 == d1 && c2 < c1)) ? 1 : 0;
            ssq = choice ? d2 : d1;             // = |z - e*|^2
        }
        choice = __shfl(choice, 0, 64);
        float2 es; es.x = choice ? e2.x : e1.x; es.y = choice ? e2.y : e1.y;
        int cs = choice ? c2 : c1;
        ((float2*)(zq + (size_t)row * DD))[lane] = es;
        if (lane == 0) {
            wsum += sqrtf(fmaxf(ssq, 0.0f));
            idsf[row] = (float)cs;
        }
    }
    if (lane == 0) bs[w] = wsum;
    __syncthreads();
    if (t == 0)
        atomicAdd(loss, (bs[0] + bs[1] + bs[2] + bs[3]) * ((1.0f + BETA) / (float)MTOT));
}

// ---------------- launcher --------------------------------------------------
extern "C" void kernel_launch(void* const* d_in, const int* in_sizes, int n_in,
                              void* d_out, int out_size, void* d_ws, size_t ws_size,
                              hipStream_t stream) {
    const float* z = (const float*)d_in[0];
    const float* e = (const float*)d_in[1];
    float* out  = (float*)d_out;
    float* zq   = out;                          // [MTOT*DD]
    float* sim  = out + (size_t)MTOT * DD;      // [MTOT*KK]
    float* idsf = sim + (size_t)MTOT * KK;      // [MTOT]
    float* loss = idsf + MTOT;                  // [1]

    // codebook bf16 hi/lo (pre-swizzled) + norms live in the workspace
    ushort* bpre = (ushort*)d_ws;               // hi: [0,262144)B, lo: [262144,524288)B
    float*  nef  = (float*)((char*)d_ws + 524288);
    float*  inef = nef + 1024;

    k_norms<<<64,        256, 0, stream>>>(e, bpre, nef, inef, loss);
    k_main <<<MTOT / TM, 256, 0, stream>>>(z, sim, bpre, nef, inef, e, zq, idsf, loss);
}

// Round 5
// 411.321 us; speedup vs baseline: 1.1943x; 1.1943x over previous
//
#include <hip/hip_runtime.h>
#include <math.h>

#define MTOT 65536   // B*T
#define DD   128
#define KK   1024
#define BETA 0.25f
#define TM   64      // rows per k_main block
#define NCH  64      // codes per chunk

typedef __attribute__((ext_vector_type(8))) short short8;
typedef __attribute__((ext_vector_type(4))) float float4v;

__device__ __forceinline__ unsigned bf16_rne(float x) {
    unsigned u = __float_as_uint(x);
    return (u + 0x7fffu + ((u >> 16) & 1u)) >> 16;
}

__device__ __forceinline__ void gload_lds16(const void* g, void* l) {
    __builtin_amdgcn_global_load_lds(
        (const __attribute__((address_space(1))) unsigned int*)g,
        (__attribute__((address_space(3))) unsigned int*)l, 16, 0, 0);
}

// --------- K0: codebook -> bf16 hi/lo PRE-SWIZZLED (for global_load_lds) ----
__global__ void k_norms(const float* __restrict__ e, ushort* __restrict__ bp,
                        float* __restrict__ nef, float* __restrict__ inef,
                        float* __restrict__ loss) {
    const int gw = blockIdx.x * 4 + (threadIdx.x >> 6);
    const int lane = threadIdx.x & 63;
    char* hb = (char*)bp;
    char* lb = hb + 262144;                   // lo part after hi part
    const int sub = lane & 3;
    for (int code = gw; code < KK; code += 256) {
        float2 ev = ((const float2*)(e + (size_t)code * DD))[lane];
        unsigned h0 = bf16_rne(ev.x), h1 = bf16_rne(ev.y);
        float l0f = ev.x - __uint_as_float(h0 << 16);
        float l1f = ev.y - __uint_as_float(h1 << 16);
        ushort2 hv; hv.x = (ushort)h0; hv.y = (ushort)h1;
        ushort2 lv; lv.x = (ushort)bf16_rne(l0f); lv.y = (ushort)bf16_rne(l1f);
        int sw = (((lane >> 2) * 16) ^ ((code & 7) << 4)) + sub * 4;
        *(ushort2*)(hb + code * 256 + sw) = hv;
        *(ushort2*)(lb + code * 256 + sw) = lv;
        float s = ev.x * ev.x + ev.y * ev.y;
        #pragma unroll
        for (int off = 32; off; off >>= 1) s += __shfl_down(s, off, 64);
        if (lane == 0) { nef[code] = s; inef[code] = 1.0f / sqrtf(s); }
    }
    if (blockIdx.x == 0 && threadIdx.x == 0) *loss = 0.0f;
}

// lexicographic (value, index) top-2 merge
__device__ __forceinline__ void merge2(float& v1, int& i1, float& v2, int& i2,
                                       float ov1, int oi1, float ov2, int oi2) {
    bool l1 = (ov1 < v1) || (ov1 == v1 && oi1 < i1);
    if (l1) {
        bool l2 = (ov2 < v1) || (ov2 == v1 && oi2 < i1);
        v2 = l2 ? ov2 : v1; i2 = l2 ? oi2 : i1;
        v1 = ov1; i1 = oi1;
    } else {
        bool l2 = (ov1 < v2) || (ov1 == v2 && oi1 < i2);
        if (l2) { v2 = ov1; i2 = oi1; }
    }
}

// --------- K1: swapped-operand MFMA + counted-vmcnt pipeline ---------------
__launch_bounds__(256, 2)
__global__ void k_main(const float* __restrict__ z, float* __restrict__ sim,
                       const ushort* __restrict__ bpre,
                       const float* __restrict__ nef, const float* __restrict__ inef,
                       const float* __restrict__ e, float* __restrict__ zq,
                       float* __restrict__ idsf, float* __restrict__ loss) {
    // 64 KB double-buffered B chunk + 8 KB codebook norms + 4 KB transpose scratch
    __shared__ __align__(16) ushort Bs[2 * 16384];
    __shared__ __align__(16) float neLf[2048];   // [0,1024): ne, [1024,2048): ine
    __shared__ __align__(16) float scr[1024];    // 1 KB per wave

    const int t = threadIdx.x;
    const int w = t >> 6, lane = t & 63, cl = lane & 15, q = lane >> 4;
    const int mh = (w & 1) * 32, nh = (w >> 1) * 32;
    const int r0 = blockIdx.x * TM;

    auto STAGE = [&](int buf, int ch2) {
        const char* gb = (const char*)bpre + (size_t)ch2 * 16384;
        #pragma unroll
        for (int i = 0; i < 8; ++i) {
            int slot = i * 256 + t;                       // 0..2047, 16B each
            int goff = slot * 16 + ((slot >= 1024) ? 245760 : 0);  // lo part adj
            gload_lds16(gb + goff,
                        (char*)Bs + buf * 32768 + (i * 256 + (t & 0xFFC0)) * 16);
        }
    };

    // codebook norms -> LDS (removes per-chunk global ne loads from vmcnt ledger)
    *(float4v*)&neLf[t * 4]        = *(const float4v*)&nef[t * 4];
    *(float4v*)&neLf[1024 + t * 4] = *(const float4v*)&inef[t * 4];

    // issue chunk-0 B staging first so it overlaps the A load/convert
    STAGE(0, 0);

    // ---- z: load directly, split to bf16 hi/lo in regs, |z|^2 per lane-row -
    short8 afh[2][4], afl[2][4];
    float pn0 = 0.0f, pn1 = 0.0f;
    const char* zb = (const char*)z;
    #pragma unroll
    for (int mt = 0; mt < 2; ++mt) {
        const char* rp = zb + (size_t)(r0 + mh + mt * 16 + cl) * 512;
        #pragma unroll
        for (int s = 0; s < 4; ++s) {
            float4v f0 = *(const float4v*)(rp + s * 128 + q * 32);
            float4v f1 = *(const float4v*)(rp + s * 128 + q * 32 + 16);
            short8 h, l;
            float ps = 0.0f;
            #pragma unroll
            for (int j = 0; j < 4; ++j) {
                float fx = f0[j];
                unsigned hu = bf16_rne(fx);
                h[j] = (short)hu;
                l[j] = (short)bf16_rne(fx - __uint_as_float(hu << 16));
                ps += fx * fx;
                float fy = f1[j];
                unsigned hw2 = bf16_rne(fy);
                h[j + 4] = (short)hw2;
                l[j + 4] = (short)bf16_rne(fy - __uint_as_float(hw2 << 16));
                ps += fy * fy;
            }
            afh[mt][s] = h; afl[mt][s] = l;
            if (mt == 0) pn0 += ps; else pn1 += ps;
        }
    }
    pn0 += __shfl_xor(pn0, 16, 64); pn0 += __shfl_xor(pn0, 32, 64);
    pn1 += __shfl_xor(pn1, 16, 64); pn1 += __shfl_xor(pn1, 32, 64);
    float inzr[2]; inzr[0] = 1.0f / sqrtf(pn0); inzr[1] = 1.0f / sqrtf(pn1);
    __syncthreads();   // single full drain: STAGE(0), neLf writes, z loads all done

    float b1v[2], b2v[2]; int b1i[2], b2i[2];
    #pragma unroll
    for (int s = 0; s < 2; ++s) { b1v[s] = 3.4e38f; b2v[s] = 3.4e38f; b1i[s] = 0; b2i[s] = 0; }

    const int swz = (cl & 7) << 4;
    float* sw = scr + w * 256;                       // wave-private 1 KB
    const int wchunk = cl * 4 + (q ^ (cl & 3));      // transpose write slot (16B units)
    const int rrow = lane >> 2, rj = lane & 3;
    const int rchunk = rrow * 4 + (rj ^ (rrow & 3)); // transpose read slot

    for (int ch = 0; ch < 16; ++ch) {
        const int c0 = ch * NCH;
        const char* Bb = (const char*)Bs + (ch & 1) * 32768;
        if (ch < 15) STAGE((ch + 1) & 1, ch + 1);   // prefetch next chunk
        __builtin_amdgcn_sched_barrier(0);          // pin prefetch issue at phase top

        float4v acc[2][2];   // [code-tile][z-tile]
        #pragma unroll
        for (int ct = 0; ct < 2; ++ct)
            #pragma unroll
            for (int zt = 0; zt < 2; ++zt) acc[ct][zt] = (float4v)(0.0f);

        // pass 0: Ch*Zh — load code-hi frags and HOLD for pass 2
        short8 bh0[4], bh1[4];
        #pragma unroll
        for (int s = 0; s < 4; ++s) {
            const int ko = (s * 64 + q * 16) ^ swz;
            bh0[s] = *(const short8*)(Bb + (nh + cl) * 256 + ko);
            bh1[s] = *(const short8*)(Bb + (nh + 16 + cl) * 256 + ko);
            acc[0][0] = __builtin_amdgcn_mfma_f32_16x16x32_bf16(bh0[s], afh[0][s], acc[0][0], 0, 0, 0);
            acc[0][1] = __builtin_amdgcn_mfma_f32_16x16x32_bf16(bh0[s], afh[1][s], acc[0][1], 0, 0, 0);
            acc[1][0] = __builtin_amdgcn_mfma_f32_16x16x32_bf16(bh1[s], afh[0][s], acc[1][0], 0, 0, 0);
            acc[1][1] = __builtin_amdgcn_mfma_f32_16x16x32_bf16(bh1[s], afh[1][s], acc[1][1], 0, 0, 0);
        }
        // pass 1: Cl*Zh
        #pragma unroll
        for (int s = 0; s < 4; ++s) {
            const int ko = (s * 64 + q * 16) ^ swz;
            short8 bl0 = *(const short8*)(Bb + 16384 + (nh + cl) * 256 + ko);
            short8 bl1 = *(const short8*)(Bb + 16384 + (nh + 16 + cl) * 256 + ko);
            acc[0][0] = __builtin_amdgcn_mfma_f32_16x16x32_bf16(bl0, afh[0][s], acc[0][0], 0, 0, 0);
            acc[0][1] = __builtin_amdgcn_mfma_f32_16x16x32_bf16(bl0, afh[1][s], acc[0][1], 0, 0, 0);
            acc[1][0] = __builtin_amdgcn_mfma_f32_16x16x32_bf16(bl1, afh[0][s], acc[1][0], 0, 0, 0);
            acc[1][1] = __builtin_amdgcn_mfma_f32_16x16x32_bf16(bl1, afh[1][s], acc[1][1], 0, 0, 0);
        }
        // pass 2: Ch*Zl (code-hi frags still in registers)
        #pragma unroll
        for (int s = 0; s < 4; ++s) {
            acc[0][0] = __builtin_amdgcn_mfma_f32_16x16x32_bf16(bh0[s], afl[0][s], acc[0][0], 0, 0, 0);
            acc[0][1] = __builtin_amdgcn_mfma_f32_16x16x32_bf16(bh0[s], afl[1][s], acc[0][1], 0, 0, 0);
            acc[1][0] = __builtin_amdgcn_mfma_f32_16x16x32_bf16(bh1[s], afl[0][s], acc[1][0], 0, 0, 0);
            acc[1][1] = __builtin_amdgcn_mfma_f32_16x16x32_bf16(bh1[s], afl[1][s], acc[1][1], 0, 0, 0);
        }

        // epilogue: codebook norms from LDS, scale, transpose-store, top-2
        float4v ne4[2], ine4[2];
        #pragma unroll
        for (int ct = 0; ct < 2; ++ct) {
            int cb = c0 + nh + ct * 16 + q * 4;
            ne4[ct]  = *(const float4v*)&neLf[cb];
            ine4[ct] = *(const float4v*)&neLf[1024 + cb];
        }
        #pragma unroll
        for (int zt = 0; zt < 2; ++zt) {
            const float inz = inzr[zt];
            #pragma unroll
            for (int ct = 0; ct < 2; ++ct) {
                const int cb = c0 + nh + ct * 16 + q * 4;
                float4v d = acc[ct][zt];
                float4v sv;
                #pragma unroll
                for (int j = 0; j < 4; ++j) sv[j] = d[j] * inz * ine4[ct][j];
                // wave-private LDS transpose: in-order DS per wave, no barrier
                *(float4v*)(sw + wchunk * 4) = sv;
                float4v ov = *(const float4v*)(sw + rchunk * 4);
                // coalesced: 4 lanes cover one full 64B line per row
                *(float4v*)(sim + (size_t)(r0 + mh + zt * 16 + rrow) * KK
                                + (c0 + nh + ct * 16 + rj * 4)) = ov;
                #pragma unroll
                for (int j = 0; j < 4; ++j) {
                    float dist = fmaf(-2.0f, d[j], ne4[ct][j]);
                    int col = cb + j;
                    if (dist < b1v[zt]) {
                        b2v[zt] = b1v[zt]; b2i[zt] = b1i[zt];
                        b1v[zt] = dist;    b1i[zt] = col;
                    } else if (dist < b2v[zt]) {
                        b2v[zt] = dist; b2i[zt] = col;
                    }
                }
            }
        }

        // counted wait: 4 stores of this chunk may float; the 8 prefetch
        // gload_lds (issued first, in-order vmcnt) are guaranteed complete.
        asm volatile("s_waitcnt vmcnt(4)" ::: "memory");
        __builtin_amdgcn_s_barrier();
        __builtin_amdgcn_sched_barrier(0);
    }

    // cross-lane merge over the 4 q-lanes (same z-row) via shfl_xor
    #pragma unroll
    for (int zt = 0; zt < 2; ++zt) {
        #pragma unroll
        for (int off = 16; off <= 32; off <<= 1) {
            float ov1 = __shfl_xor(b1v[zt], off, 64);
            int   oi1 = __shfl_xor(b1i[zt], off, 64);
            float ov2 = __shfl_xor(b2v[zt], off, 64);
            int   oi2 = __shfl_xor(b2i[zt], off, 64);
            merge2(b1v[zt], b1i[zt], b2v[zt], b2i[zt], ov1, oi1, ov2, oi2);
        }
    }
    // cross-wave (two code halves) merge via tiny LDS table in Bs (free now)
    float* top = (float*)Bs;
    if (q == 0) {
        #pragma unroll
        for (int zt = 0; zt < 2; ++zt) {
            int row = mh + zt * 16 + cl;
            float4v v;
            v[0] = b1v[zt]; v[1] = __int_as_float(b1i[zt]);
            v[2] = b2v[zt]; v[3] = __int_as_float(b2i[zt]);
            *(float4v*)(top + (row * 2 + (w >> 1)) * 4) = v;
        }
    }
    __syncthreads();
    unsigned* candL = (unsigned*)scr;          // scratch is free after the loop
    float* bsum = scr + 64;
    if (t < TM) {
        float4v e0 = *(const float4v*)(top + (t * 2 + 0) * 4);
        float4v e1 = *(const float4v*)(top + (t * 2 + 1) * 4);
        float v1 = e0[0], v2 = e0[2];
        int   i1 = __float_as_int(e0[1]), i2 = __float_as_int(e0[3]);
        merge2(v1, i1, v2, i2, e1[0], __float_as_int(e1[1]), e1[2], __float_as_int(e1[3]));
        candL[t] = (unsigned)i1 | ((unsigned)i2 << 16);
    }
    __syncthreads();

    // ---- fused exact fp32 re-rank of top-2 (identical math to old K2) ------
    float wsum = 0.0f;
    const int rloc = w * 16;
    for (int i = 0; i < 16; ++i) {
        int row = r0 + rloc + i;
        unsigned pk = candL[rloc + i];
        int c1 = (int)(pk & 0xffffu), c2 = (int)(pk >> 16);
        float2 zv = ((const float2*)(z + (size_t)row * DD))[lane];
        float2 e1 = ((const float2*)(e + (size_t)c1 * DD))[lane];
        float2 e2 = ((const float2*)(e + (size_t)c2 * DD))[lane];
        float v0 = zv.x * zv.x + zv.y * zv.y;   // |z|^2
        float v1 = zv.x * e1.x + zv.y * e1.y;   // z.e1
        float v2 = zv.x * e2.x + zv.y * e2.y;   // z.e2
        float v3 = e1.x * e1.x + e1.y * e1.y;   // |e1|^2
        float v4 = e2.x * e2.x + e2.y * e2.y;   // |e2|^2
        #pragma unroll
        for (int off = 32; off; off >>= 1) {
            v0 += __shfl_down(v0, off, 64);
            v1 += __shfl_down(v1, off, 64);
            v2 += __shfl_down(v2, off, 64);
            v3 += __shfl_down(v3, off, 64);
            v4 += __shfl_down(v4, off, 64);
        }
        int choice = 0; float ssq = 0.0f;
        if (lane == 0) {
            float d1 = fmaf(-2.0f, v1, v0 + v3);
            float d2 = fmaf(-2.0f, v2, v0 + v4);
            choice = (d2 < d1 || (d2 == d1 && c2 < c1)) ? 1 : 0;
            ssq = choice ? d2 : d1;             // = |z - e*|^2
        }
        choice = __shfl(choice, 0, 64);
        float2 es; es.x = choice ? e2.x : e1.x; es.y = choice ? e2.y : e1.y;
        int cs = choice ? c2 : c1;
        ((float2*)(zq + (size_t)row * DD))[lane] = es;
        if (lane == 0) {
            wsum += sqrtf(fmaxf(ssq, 0.0f));
            idsf[row] = (float)cs;
        }
    }
    if (lane == 0) bsum[w] = wsum;
    __syncthreads();
    if (t == 0)
        atomicAdd(loss, (bsum[0] + bsum[1] + bsum[2] + bsum[3]) * ((1.0f + BETA) / (float)MTOT));
}

// ---------------- launcher --------------------------------------------------
extern "C" void kernel_launch(void* const* d_in, const int* in_sizes, int n_in,
                              void* d_out, int out_size, void* d_ws, size_t ws_size,
                              hipStream_t stream) {
    const float* z = (const float*)d_in[0];
    const float* e = (const float*)d_in[1];
    float* out  = (float*)d_out;
    float* zq   = out;                          // [MTOT*DD]
    float* sim  = out + (size_t)MTOT * DD;      // [MTOT*KK]
    float* idsf = sim + (size_t)MTOT * KK;      // [MTOT]
    float* loss = idsf + MTOT;                  // [1]

    // codebook bf16 hi/lo (pre-swizzled) + norms live in the workspace
    ushort* bpre = (ushort*)d_ws;               // hi: [0,262144)B, lo: [262144,524288)B
    float*  nef  = (float*)((char*)d_ws + 524288);
    float*  inef = nef + 1024;

    k_norms<<<64,        256, 0, stream>>>(e, bpre, nef, inef, loss);
    k_main <<<MTOT / TM, 256, 0, stream>>>(z, sim, bpre, nef, inef, e, zq, idsf, loss);
}